// Round 5
// baseline (572.042 us; speedup 1.0000x reference)
//
#include <hip/hip_runtime.h>
#include <hip/hip_bf16.h>

// Problem constants (GCN autoencoder)
#define N_NODES 10000
#define N_FEAT  512
#define HIDDEN  32
#define CODE    16

typedef __attribute__((ext_vector_type(8))) short  short8;
typedef __attribute__((ext_vector_type(4))) float  floatx4;

__device__ __forceinline__ float bf2f(unsigned short h) {
    return __uint_as_float(((unsigned int)h) << 16);
}
__device__ __forceinline__ unsigned short f2bf(float f) {
    unsigned int u = __float_as_uint(f);
    u += 0x7fffu + ((u >> 16) & 1u);   // RNE
    return (unsigned short)(u >> 16);
}
__device__ __forceinline__ float load_f(const void* p, size_t i, int isf32) {
    return isf32 ? ((const float*)p)[i] : bf2f(((const unsigned short*)p)[i]);
}
__device__ __forceinline__ int get_idx(const int* p, int e, int is64) {
    return is64 ? p[2 * (size_t)e] : p[e];   // LE low half holds value (<10000)
}

// ---------------------------------------------------------------------------
// K0: dtype detector (insurance). Waves 0..3: {x,W1,W2,ew} fp32-vs-bf16 via
// low-mantissa entropy. Waves 4..5: {src,dst} int64-vs-int32 via zero highs.
// ---------------------------------------------------------------------------
__global__ __launch_bounds__(384) void k_detect(const unsigned short* __restrict__ t0,
                                                const unsigned short* __restrict__ t1,
                                                const unsigned short* __restrict__ t2,
                                                const unsigned short* __restrict__ t3,
                                                const int* __restrict__ i0,
                                                const int* __restrict__ i1,
                                                int* __restrict__ flags) {
    const int w    = threadIdx.x >> 6;
    const int lane = threadIdx.x & 63;
    unsigned int m = 0;
    if (w < 4) {
        const unsigned short* p = (w == 0) ? t0 : (w == 1) ? t1 : (w == 2) ? t2 : t3;
        for (int i = lane; i < 128; i += 64) {
            unsigned int v = (unsigned int)p[2 * i] & 0x7fffu;
            m = m > v ? m : v;
        }
    } else {
        const int* p = (w == 4) ? i0 : i1;
        for (int i = lane; i < 128; i += 64) {
            m |= (unsigned int)p[2 * i + 1];
        }
    }
#pragma unroll
    for (int off = 32; off > 0; off >>= 1) {
        unsigned int o = (unsigned int)__shfl_down((int)m, off, 64);
        m = (w < 4) ? (m > o ? m : o) : (m | o);
    }
    if (lane == 0) flags[w] = (w < 4) ? (m >= 0x5000u ? 1 : 0) : (m == 0u ? 1 : 0);
}

// ---------------------------------------------------------------------------
// CSR build: histogram of dst -> exclusive scan -> scatter edges sorted by dst.
// Replaces 15.8M fp32 atomics with 660k int atomics.
// ---------------------------------------------------------------------------
__global__ __launch_bounds__(256) void k_hist(const int* __restrict__ dst,
                                              int* __restrict__ cnt, int E,
                                              const int* __restrict__ flags) {
    const int d64 = flags[5];
    int t = blockIdx.x * 256 + threadIdx.x;
    if (t >= E) return;
    atomicAdd(&cnt[get_idx(dst, t, d64)], 1);
}

// single block, 256 threads, 40 rows per thread (40*250 = 10000)
__global__ __launch_bounds__(256) void k_scan(const int* __restrict__ cnt,
                                              int* __restrict__ rowptr) {
    __shared__ int sdata[256];
    const int t = threadIdx.x;
    const int base = t * 40;
    int p = 0;
    for (int j = 0; j < 40; ++j) {
        int i = base + j;
        if (i < N_NODES) p += cnt[i];
    }
    sdata[t] = p;
    __syncthreads();
    for (int off = 1; off < 256; off <<= 1) {
        int v = (t >= off) ? sdata[t - off] : 0;
        __syncthreads();
        sdata[t] += v;
        __syncthreads();
    }
    int run = sdata[t] - p;   // exclusive prefix of this thread's segment
    for (int j = 0; j < 40; ++j) {
        int i = base + j;
        if (i < N_NODES) { rowptr[i] = run; run += cnt[i]; }
    }
    if (t == 255) rowptr[N_NODES] = sdata[255];
}

__global__ __launch_bounds__(256) void k_scatter(const int* __restrict__ src,
                                                 const int* __restrict__ dst,
                                                 const void* __restrict__ ew,
                                                 const int* __restrict__ rowptr,
                                                 int* __restrict__ fill,
                                                 int* __restrict__ srcS,
                                                 float* __restrict__ wS, int E,
                                                 const int* __restrict__ flags) {
    const int ewf32 = flags[3];
    const int s64   = flags[4];
    const int d64   = flags[5];
    int t = blockIdx.x * 256 + threadIdx.x;
    if (t >= E) return;
    int d = get_idx(dst, t, d64);
    int pos = rowptr[d] + atomicAdd(&fill[d], 1);
    srcS[pos] = get_idx(src, t, s64);
    wS[pos]   = load_f(ew, t, ewf32);
}

// ---------------------------------------------------------------------------
// K1: XW1 = x @ W1  [10000x512] @ [512x32] -> fp32 (VALU; x row L1-broadcast)
// ---------------------------------------------------------------------------
__global__ __launch_bounds__(256) void k_xw1(const void* __restrict__ x,
                                             const void* __restrict__ W1,
                                             float* __restrict__ XW1,
                                             const int* __restrict__ flags) {
    const int xf32  = flags[0];
    const int w1f32 = flags[1];
    int t = blockIdx.x * 256 + threadIdx.x;
    if (t >= N_NODES * HIDDEN) return;
    const int n = t >> 5;
    const int c = t & 31;
    float acc = 0.f;
#pragma unroll 8
    for (int k = 0; k < N_FEAT; ++k) {
        float a = load_f(x,  (size_t)n * N_FEAT + k, xf32);
        float b = load_f(W1, (size_t)k * HIDDEN + c, w1f32);
        acc += a * b;
    }
    XW1[t] = acc;
}

// ---------------------------------------------------------------------------
// K2: pull-SpMM over CSR, 32 feats: half-wave per row, relu fused.
// No atomics; every Hacc element written exactly once.
// ---------------------------------------------------------------------------
__global__ __launch_bounds__(256) void k_gather32(const int* __restrict__ rowptr,
                                                  const int* __restrict__ srcS,
                                                  const float* __restrict__ wS,
                                                  const float* __restrict__ XW1,
                                                  float* __restrict__ Hacc) {
    const int lane = threadIdx.x & 63;
    const int gw   = blockIdx.x * 4 + (threadIdx.x >> 6);
    const int n    = gw * 2 + (lane >> 5);
    const int f    = lane & 31;
    if (n >= N_NODES) return;
    const int s0 = rowptr[n], s1 = rowptr[n + 1];
    float acc = 0.f;
    for (int j = s0; j < s1; ++j) {
        acc += wS[j] * XW1[(size_t)srcS[j] * HIDDEN + f];
    }
    Hacc[(size_t)n * HIDDEN + f] = fmaxf(acc, 0.f);
}

// ---------------------------------------------------------------------------
// K3: HW2 = Hacc @ W2   [10000x32] @ [32x16] -> fp32  (Hacc already relu'd)
// ---------------------------------------------------------------------------
__global__ __launch_bounds__(256) void k_hw2(const float* __restrict__ H,
                                             const void* __restrict__ W2,
                                             float* __restrict__ HW2,
                                             const int* __restrict__ flags) {
    const int w2f32 = flags[2];
    int t = blockIdx.x * 256 + threadIdx.x;
    if (t >= N_NODES * CODE) return;
    int n = t >> 4;
    int c = t & 15;
    float acc = 0.f;
#pragma unroll
    for (int k = 0; k < HIDDEN; ++k) {
        acc += H[n * HIDDEN + k] * load_f(W2, k * CODE + c, w2f32);
    }
    HW2[t] = acc;
}

// ---------------------------------------------------------------------------
// K4: pull-SpMM over CSR, 16 feats: quarter-wave per row, f2bf fused -> zb.
// ---------------------------------------------------------------------------
__global__ __launch_bounds__(256) void k_gather16(const int* __restrict__ rowptr,
                                                  const int* __restrict__ srcS,
                                                  const float* __restrict__ wS,
                                                  const float* __restrict__ HW2,
                                                  unsigned short* __restrict__ zb) {
    const int lane = threadIdx.x & 63;
    const int gw   = blockIdx.x * 4 + (threadIdx.x >> 6);
    const int n    = gw * 4 + (lane >> 4);
    const int f    = lane & 15;
    if (n >= N_NODES) return;
    const int s0 = rowptr[n], s1 = rowptr[n + 1];
    float acc = 0.f;
    for (int j = s0; j < s1; ++j) {
        acc += wS[j] * HW2[(size_t)srcS[j] * CODE + f];
    }
    zb[(size_t)n * CODE + f] = f2bf(acc);
}

// ---------------------------------------------------------------------------
// K6: out = sigmoid(zb @ zb^T), FP32 out [10000x10000] (400 MB, write-bound).
// Symmetry trick: acc[t][r] is S[row][col]=S[col][row]; storing at
// out[col*N + row] makes the r-axis stride-1 -> float4 stores.
// N % 4 == 0 so a float4 never straddles the boundary; rb<N guard is exact.
// ---------------------------------------------------------------------------
__global__ __launch_bounds__(256) void k_dec(const unsigned short* __restrict__ zb,
                                             float* __restrict__ out) {
    const int wave = threadIdx.x >> 6;
    const int lane = threadIdx.x & 63;
    const int l16  = lane & 15;
    const int quad = lane >> 4;

    const int r0 = blockIdx.y * 64 + wave * 16;
    const int c0 = blockIdx.x * 64;

    const short8 zero8 = {0, 0, 0, 0, 0, 0, 0, 0};

    int ra = r0 + l16;
    if (ra > N_NODES - 1) ra = N_NODES - 1;
    short8 afr = zero8;
    if (quad < 2) afr = *(const short8*)(zb + (size_t)ra * CODE + quad * 8);

    floatx4 acc[4];
#pragma unroll
    for (int t = 0; t < 4; ++t) {
        int cb = c0 + t * 16 + l16;
        if (cb > N_NODES - 1) cb = N_NODES - 1;
        short8 bfr = zero8;
        if (quad < 2) bfr = *(const short8*)(zb + (size_t)cb * CODE + quad * 8);
        floatx4 z4 = {0.f, 0.f, 0.f, 0.f};
        acc[t] = __builtin_amdgcn_mfma_f32_16x16x32_bf16(afr, bfr, z4, 0, 0, 0);
    }

    const int rb = r0 + quad * 4;          // row base for this lane's 4 regs
#pragma unroll
    for (int t = 0; t < 4; ++t) {
        int col = c0 + t * 16 + l16;
        floatx4 v;
#pragma unroll
        for (int r = 0; r < 4; ++r) {
            float s = acc[t][r];
            float e = __builtin_amdgcn_exp2f(-1.442695041f * s);
            v[r] = __builtin_amdgcn_rcpf(1.f + e);
        }
        if (col < N_NODES && rb < N_NODES) {
            *(floatx4*)(out + (size_t)col * N_NODES + rb) = v;
        }
    }
}

// ---------------------------------------------------------------------------
extern "C" void kernel_launch(void* const* d_in, const int* in_sizes, int n_in,
                              void* d_out, int out_size, void* d_ws, size_t ws_size,
                              hipStream_t stream) {
    const void* x  = d_in[0];
    const void* W1 = d_in[1];
    const void* W2 = d_in[2];
    const void* ew = d_in[3];
    const int* src = (const int*)d_in[4];
    const int* dst = (const int*)d_in[5];
    float* out = (float*)d_out;
    const int E = in_sizes[3];   // 330000 edges

    // Workspace (float offsets):
    //  XW1   [0, 320000)           HW2  [0, 160000)  (after XW1 dead)
    //  Hacc  [320000, 640000)      zb ushort @ 320000 (after Hacc dead)
    //  flags int[6] @ 640000
    //  cnt   int[10000] @ 700000   fill int[10000] @ 710000  (one memset)
    //  rowptr int[10001] @ 720000  srcS int[E] @ 730016      wS float[E] after
    float* ws   = (float*)d_ws;
    float* XW1  = ws;
    float* Hacc = ws + 320000;
    float* HW2  = ws;
    unsigned short* zb = (unsigned short*)(ws + 320000);
    int* flags  = (int*)(ws + 640000);
    int* cnt    = (int*)(ws + 700000);
    int* fill   = (int*)(ws + 710000);
    int* rowptr = (int*)(ws + 720000);
    int* srcS   = (int*)(ws + 730016);
    float* wS   = (float*)(srcS + E);

    hipMemsetAsync(cnt, 0, 20000 * sizeof(int), stream);   // cnt + fill

    k_detect<<<1, 384, 0, stream>>>((const unsigned short*)x,
                                    (const unsigned short*)W1,
                                    (const unsigned short*)W2,
                                    (const unsigned short*)ew,
                                    src, dst, flags);

    k_hist   <<<(E + 255) / 256, 256, 0, stream>>>(dst, cnt, E, flags);
    k_scan   <<<1, 256, 0, stream>>>(cnt, rowptr);
    k_scatter<<<(E + 255) / 256, 256, 0, stream>>>(src, dst, ew, rowptr, fill,
                                                   srcS, wS, E, flags);

    k_xw1     <<<(N_NODES * HIDDEN + 255) / 256, 256, 0, stream>>>(x, W1, XW1, flags);
    k_gather32<<<(N_NODES + 7) / 8, 256, 0, stream>>>(rowptr, srcS, wS, XW1, Hacc);
    k_hw2     <<<(N_NODES * CODE + 255) / 256, 256, 0, stream>>>(Hacc, W2, HW2, flags);
    k_gather16<<<(N_NODES + 15) / 16, 256, 0, stream>>>(rowptr, srcS, wS, HW2, zb);

    dim3 grid((N_NODES + 63) / 64, (N_NODES + 63) / 64);
    k_dec<<<grid, 256, 0, stream>>>(zb, out);
}